// Round 12
// baseline (6169.429 us; speedup 1.0000x reference)
//
#include <hip/hip_runtime.h>
#include <cstdint>
#include <cstddef>

#define B_ 256
#define S_ 512
#define FASTK 256

typedef _Float16 f16;
typedef _Float16 f16x8 __attribute__((ext_vector_type(8)));
typedef _Float16 f16x4 __attribute__((ext_vector_type(4)));
typedef float f32x4 __attribute__((ext_vector_type(4)));
typedef unsigned int u32x4 __attribute__((ext_vector_type(4)));
using u32 = unsigned int;
using u16 = unsigned short;
using u64 = unsigned long long;

#define TAGX   0x555u
#define MAGIC_ 0x13579BDFu

__device__ __forceinline__ float sigf(float x) { return 1.f / (1.f + __expf(-x)); }
__device__ __forceinline__ float tanh_f(float x) {
  x = fminf(15.f, fmaxf(-15.f, x));
  const float e = __expf(-2.f * x);
  return (1.f - e) / (1.f + e);
}
__device__ __forceinline__ f16x8 cvt_f16x8(float4 a, float4 b) {
  f16x8 t;
  t[0] = (f16)a.x; t[1] = (f16)a.y; t[2] = (f16)a.z; t[3] = (f16)a.w;
  t[4] = (f16)b.x; t[5] = (f16)b.y; t[6] = (f16)b.z; t[7] = (f16)b.w;
  return t;
}

// same-XCD L2 fast-path primitives: plain store (lands in XCD L2), sc0 load
// (L1-bypass, served by XCD L2). Correctness does NOT depend on XCD
// co-residency: a sc1 shadow copy always exists (sticky poll fallback).
__device__ __forceinline__ void fast_store(u64* p, u64 v) {
  asm volatile("global_store_dwordx2 %0, %1, off" :: "v"(p), "v"(v) : "memory");
}
__device__ __forceinline__ void fast_load4(const u64* p0, const u64* p1,
                                           const u64* p2, const u64* p3,
                                           u32x4& a, u32x4& b, u32x4& c, u32x4& d) {
  asm volatile(
      "global_load_dwordx4 %0, %4, off sc0\n\t"
      "global_load_dwordx4 %1, %5, off sc0\n\t"
      "global_load_dwordx4 %2, %6, off sc0\n\t"
      "global_load_dwordx4 %3, %7, off sc0\n\t"
      "s_waitcnt vmcnt(0)"
      : "=&v"(a), "=&v"(b), "=&v"(c), "=&v"(d)
      : "v"(p0), "v"(p1), "v"(p2), "v"(p3)
      : "memory");
}

// ---------------------------------------------------------------------------
// x transpose+convert: x[b][t][64] fp32 -> xT[t][b][64] f16
// ---------------------------------------------------------------------------
__global__ __launch_bounds__(256) void transpose_x(
    const float* __restrict__ x, f16* __restrict__ xT)
{
  const int t = blockIdx.x;
  const int col = threadIdx.x & 63;
  const int r0 = threadIdx.x >> 6;
  for (int it = 0; it < 64; ++it) {
    const int row = (it << 2) + r0;
    xT[((size_t)t * 256 + row) * 64 + col] =
        (f16)x[((size_t)row * S_ + t) * 64 + col];
  }
}

// ---------------------------------------------------------------------------
// Persistent fused BiLSTM layer (r7 geometry: 256 wgs = 1/CU, 256 thr).
// wg = dir*128 + bg*8 + sl : 16 batch rows x 32 h-units (128 gate cols).
// Weights in registers (W_ih f16; W_hh f16 hi + lo*2^10). h exchanged via
// tagged-f32 parity ring, DUAL-published: fast copy (same-XCD L2) + sc1
// shadow. Consumer: parallel 4x dwordx4 poll with s_sleep(2) throttle,
// FASTK tries, then sticky sc1 fallback.
// ---------------------------------------------------------------------------
template<int L, int KIN>
__global__ __launch_bounds__(256, 1) void lstm_layer(
    const f16* __restrict__ xT,     // [512][256][64]   (L0 input)
    f16* __restrict__ hA,           // [512][256][512]
    f16* __restrict__ aux,          // [2][256][256][256]
    f16* __restrict__ l2out,        // [256][512]
    u64* __restrict__ exch,         // sc1 shadow ring [2][2][256][128]
    u64* __restrict__ exchF,        // fast ring       [2][2][256][128]
    u32* __restrict__ xprog,        // [2][128]
    const float* __restrict__ w_ih, // [2][1024][KIN]
    const float* __restrict__ w_hh, // [2][1024][256]
    const float* __restrict__ bias) // [2][1024]
{
  constexpr int GPR = KIN / 8;
  constexpr int LG  = (KIN == 512) ? 6 : 3;
  constexpr int NG  = 16 * GPR;
  constexpr int XI  = (NG + 255) / 256;
  __shared__ __align__(16) f16 x_s[16 * KIN];
  __shared__ __align__(16) f16 h_s[16 * 256];
  __shared__ float gates_s[64 * 35];
  __shared__ char pad_[81920];              // force 1 wg/CU

  const int tid = threadIdx.x;
  const int lane = tid & 63, w = tid >> 6;
  const int l15 = lane & 15, l4 = lane >> 4;
  const int phys = blockIdx.x;
  const int wg = ((phys & 7) << 5) | (phys >> 3);  // co-locate groups per XCD
  const int dirv = wg >> 7, bg = (wg >> 3) & 15, sl = wg & 7;
  if ((int)blockIdx.x == -1) pad_[tid] = 0;

  // ---- weight slices -> registers ----
  f16x8 bih[2][KIN / 32];
  f16x8 bhhH[2][8], bhhL[2][8];
#pragma unroll
  for (int nt = 0; nt < 2; ++nt) {
    const int grow = (w << 8) + (sl << 5) + (nt << 4) + l15;
    const float* pih = w_ih + ((size_t)(dirv << 10) + grow) * KIN + (l4 << 3);
#pragma unroll
    for (int kt = 0; kt < KIN / 32; ++kt) {
      const float* p = pih + (kt << 5);
      bih[nt][kt] = cvt_f16x8(*(const float4*)p, *(const float4*)(p + 4));
    }
    const float* phh = w_hh + ((size_t)(dirv << 10) + grow) * 256 + (l4 << 3);
#pragma unroll
    for (int kt = 0; kt < 8; ++kt) {
      const float* p = phh + (kt << 5);
      float wf[8];
      *(float4*)&wf[0] = *(const float4*)p;
      *(float4*)&wf[4] = *(const float4*)(p + 4);
      f16x8 hi, lo;
#pragma unroll
      for (int j = 0; j < 8; ++j) {
        hi[j] = (f16)wf[j];
        lo[j] = (f16)((wf[j] - (float)hi[j]) * 1024.f);
      }
      bhhH[nt][kt] = hi;
      bhhL[nt][kt] = lo;
    }
  }

  const int crow = tid >> 4;
  const int u0 = (tid & 15) << 1;
  float bv[4][2];
#pragma unroll
  for (int g = 0; g < 4; ++g)
#pragma unroll
    for (int j = 0; j < 2; ++j)
      bv[g][j] = bias[(dirv << 10) + (g << 8) + (sl << 5) + u0 + j];
  float cs0 = 0.f, cs1 = 0.f;
  bool slow = false;                 // sticky fallback to sc1 shadow

  auto xsrc = [&](int t, int b, int g) -> const f16* {
    if constexpr (L == 0) {
      return xT + ((size_t)t * 256 + b) * 64 + (g << 3);
    } else if constexpr (L == 1) {
      return hA + ((size_t)t * 256 + b) * 512 + (g << 3);
    } else {
      const int c0 = g << 3;
      if (c0 < 256)
        return (t < 256) ? aux + ((size_t)t * 256 + b) * 256 + c0
                         : hA + ((size_t)t * 256 + b) * 512 + c0;
      const int u = c0 - 256;
      return (t >= 256) ? aux + ((size_t)(256 + (511 - t)) * 256 + b) * 256 + u
                        : hA + ((size_t)t * 256 + b) * 512 + 256 + u;
    }
  };

#define X_MFMA(A0, A1)                                                         \
  {                                                                            \
    _Pragma("unroll")                                                          \
    for (int kt = 0; kt < KIN / 32; ++kt) {                                    \
      const int gg = ((kt << 2) + l4) ^ (l15 & 7);                             \
      const f16x8 a = *(const f16x8*)&x_s[l15 * KIN + (gg << 3)];              \
      A0 = __builtin_amdgcn_mfma_f32_16x16x32_f16(a, bih[0][kt], A0, 0, 0, 0); \
      A1 = __builtin_amdgcn_mfma_f32_16x16x32_f16(a, bih[1][kt], A1, 0, 0, 0); \
    }                                                                          \
  }

  // ---- prologue ----
  f16x8 xreg[XI];
  {
    const int t0 = dirv ? (S_ - 1) : 0;
#pragma unroll
    for (int i = 0; i < XI; ++i) {
      const int G = tid + (i << 8);
      if (NG < 256 && G >= NG) break;
      const int row = G >> LG, g = G & (GPR - 1);
      xreg[i] = *(const f16x8*)xsrc(t0, (bg << 4) + row, g);
    }
#pragma unroll
    for (int i = 0; i < XI; ++i) {
      const int G = tid + (i << 8);
      if (NG < 256 && G >= NG) break;
      const int row = G >> LG, g = G & (GPR - 1);
      *(f16x8*)&x_s[row * KIN + ((g ^ (row & 7)) << 3)] = xreg[i];
    }
  }
  __syncthreads();
  f32x4 accx0 = {}, accx1 = {};
  X_MFMA(accx0, accx1);

  for (int s = 0; s < S_; ++s) {
    const int t_or = dirv ? (S_ - 1 - s) : s;
    const bool pf = (s + 1 < S_);

    // ---- issue x prefetch for step s+1 ----
    if (pf) {
      const int t_nx = dirv ? (t_or - 1) : (t_or + 1);
#pragma unroll
      for (int i = 0; i < XI; ++i) {
        const int G = tid + (i << 8);
        if (NG < 256 && G >= NG) break;
        const int row = G >> LG, g = G & (GPR - 1);
        xreg[i] = *(const f16x8*)xsrc(t_nx, (bg << 4) + row, g);
      }
    }

    // ---- L1 crossover gate ----
    if constexpr (L == 1) {
      if (s == 256) {
        if (tid < 128) {
          const u32* pw = xprog + (1 - dirv) * 128 + tid;
          while (__hip_atomic_load(pw, __ATOMIC_RELAXED, __HIP_MEMORY_SCOPE_AGENT) != MAGIC_)
            __builtin_amdgcn_s_sleep(2);
        }
        __syncthreads();
      }
    }

    // ---- stage h(s-1): throttled fast poll, sticky sc1 fallback ----
    if (s > 0) {
      const u32 tagp = ((u32)(L * 512 + s - 1) ^ TAGX) & 0x7FFu;
      const size_t ebase = ((size_t)(((s - 1) & 1) * 2 + dirv)) * 256 * 128;
      u32x4 q[4];
      const u64* pp[4];
#pragma unroll
      for (int i = 0; i < 4; ++i) {
        const int G = tid + (i << 8);
        const int row = G >> 6, gr = G & 63;
        pp[i] = exchF + ebase + ((bg << 4) + row) * 128 + (gr << 1);
      }
      bool got = false;
      if (!slow) {
        for (int tr = 0; tr < FASTK && !got; ++tr) {
          fast_load4(pp[0], pp[1], pp[2], pp[3], q[0], q[1], q[2], q[3]);
          bool ok = true;
#pragma unroll
          for (int i = 0; i < 4; ++i)
#pragma unroll
            for (int j = 0; j < 4; ++j) ok &= ((q[i][j] & 0x7FFu) == tagp);
          if (ok) got = true;
          else __builtin_amdgcn_s_sleep(2);
        }
        if (!got) slow = true;
      }
      if (!got) {
        // correctness path: sc1 shadow (coherence point), mapping-independent
        for (;;) {
          bool ok = true;
#pragma unroll
          for (int i = 0; i < 4; ++i) {
            const int G = tid + (i << 8);
            const int row = G >> 6, gr = G & 63;
            const u64* p = exch + ebase + ((bg << 4) + row) * 128 + (gr << 1);
            const u64 a = __hip_atomic_load(p, __ATOMIC_RELAXED, __HIP_MEMORY_SCOPE_AGENT);
            const u64 c = __hip_atomic_load(p + 1, __ATOMIC_RELAXED, __HIP_MEMORY_SCOPE_AGENT);
            q[i][0] = (u32)a; q[i][1] = (u32)(a >> 32);
            q[i][2] = (u32)c; q[i][3] = (u32)(c >> 32);
#pragma unroll
            for (int j = 0; j < 4; ++j) ok &= ((q[i][j] & 0x7FFu) == tagp);
          }
          if (ok) break;
          __builtin_amdgcn_s_sleep(1);
        }
      }
#pragma unroll
      for (int i = 0; i < 4; ++i) {
        const int G = tid + (i << 8);
        const int row = G >> 6, gr = G & 63;
        const int g8 = gr >> 1, half = gr & 1;
        f16x4 hh;
#pragma unroll
        for (int j = 0; j < 4; ++j)
          hh[j] = (f16)__builtin_bit_cast(float, q[i][j] & 0xFFFFF800u);
        *(f16x4*)&h_s[(row << 8) + ((g8 ^ (row & 7)) << 3) + (half << 2)] = hh;
      }
    }
    __syncthreads();                               // h_s staged

    // ---- MFMAs ----
    f32x4 acc0 = accx0, acc1 = accx1;
    if (s > 0) {
      f32x4 aL0 = {}, aL1 = {};
#pragma unroll
      for (int kt = 0; kt < 8; ++kt) {
        const int gg = ((kt << 2) + l4) ^ (l15 & 7);
        const f16x8 a = *(const f16x8*)&h_s[(l15 << 8) + (gg << 3)];
        acc0 = __builtin_amdgcn_mfma_f32_16x16x32_f16(a, bhhH[0][kt], acc0, 0, 0, 0);
        acc1 = __builtin_amdgcn_mfma_f32_16x16x32_f16(a, bhhH[1][kt], acc1, 0, 0, 0);
        aL0 = __builtin_amdgcn_mfma_f32_16x16x32_f16(a, bhhL[0][kt], aL0, 0, 0, 0);
        aL1 = __builtin_amdgcn_mfma_f32_16x16x32_f16(a, bhhL[1][kt], aL1, 0, 0, 0);
      }
      acc0 += aL0 * (1.f / 1024.f);
      acc1 += aL1 * (1.f / 1024.f);
    }

    // ---- gate preacts -> LDS ----
#pragma unroll
    for (int r = 0; r < 4; ++r) {
      const int row = (l4 << 2) + r;
      gates_s[((w << 4) + row) * 35 + l15] = acc0[r];
      gates_s[((w << 4) + row) * 35 + 16 + l15] = acc1[r];
    }
    __syncthreads();

    // ---- cell update ----
    float hv[2];
    {
      float css[2] = { cs0, cs1 };
#pragma unroll
      for (int j = 0; j < 2; ++j) {
        const int u = u0 + j;
        const float gi = gates_s[(0 * 16 + crow) * 35 + u] + bv[0][j];
        const float gf = gates_s[(1 * 16 + crow) * 35 + u] + bv[1][j];
        const float gg = gates_s[(2 * 16 + crow) * 35 + u] + bv[2][j];
        const float go = gates_s[(3 * 16 + crow) * 35 + u] + bv[3][j];
        float cc = sigf(gf) * css[j] + sigf(gi) * tanh_f(gg);
        css[j] = cc;
        hv[j] = sigf(go) * tanh_f(cc);
      }
      cs0 = css[0]; cs1 = css[1];
    }

    // ---- publish h(s): fast + shadow; bulk stores after ----
    if (L == 1 && s >= 253) asm volatile("s_waitcnt vmcnt(0)" ::: "memory");
    {
      const u32 tagc = ((u32)(L * 512 + s) ^ TAGX) & 0x7FFu;
      const u32 w0 = ((__builtin_bit_cast(u32, hv[0]) + 0x400u) & 0xFFFFF800u) | tagc;
      const u32 w1 = ((__builtin_bit_cast(u32, hv[1]) + 0x400u) & 0xFFFFF800u) | tagc;
      const u64 pk = (u64)w0 | ((u64)w1 << 32);
      const int b = (bg << 4) + crow;
      const size_t eidx = ((size_t)((s & 1) * 2 + dirv)) * 256 * 128 + b * 128 + (sl << 4) + (u0 >> 1);
      fast_store(exchF + eidx, pk);
      __hip_atomic_store(exch + eidx, pk, __ATOMIC_RELAXED, __HIP_MEMORY_SCOPE_AGENT);

      union { u16 hw[2]; u32 pkh; } uh;
      uh.hw[0] = __builtin_bit_cast(u16, (f16)hv[0]);
      uh.hw[1] = __builtin_bit_cast(u16, (f16)hv[1]);
      const int uoff = (dirv << 7) + (sl << 4) + (u0 >> 1);
      if constexpr (L == 0) {
        ((u32*)hA)[((size_t)t_or * 256 + b) * 256 + uoff] = uh.pkh;
      } else if constexpr (L == 1) {
        if (s < 256)
          ((u32*)aux)[((size_t)(dirv * 256 + s) * 256 + b) * 128 + (sl << 4) + (u0 >> 1)] = uh.pkh;
        else
          ((u32*)hA)[((size_t)t_or * 256 + b) * 256 + uoff] = uh.pkh;
      } else {
        if (t_or == S_ - 1)
          ((u32*)l2out)[(size_t)b * 256 + uoff] = uh.pkh;
      }
    }

    // ---- L1: crossover MAGIC after h(254) globally posted ----
    if constexpr (L == 1) {
      if (s == 254) {
        asm volatile("s_waitcnt vmcnt(0)" ::: "memory");
        __syncthreads();
        if (tid == 0)
          __hip_atomic_store(xprog + dirv * 128 + (bg << 3) + sl, MAGIC_,
                             __ATOMIC_RELAXED, __HIP_MEMORY_SCOPE_AGENT);
      }
    }

    // ---- write x_s for s+1 and pre-compute its x-part ----
    if (pf) {
#pragma unroll
      for (int i = 0; i < XI; ++i) {
        const int G = tid + (i << 8);
        if (NG < 256 && G >= NG) break;
        const int row = G >> LG, g = G & (GPR - 1);
        *(f16x8*)&x_s[row * KIN + ((g ^ (row & 7)) << 3)] = xreg[i];
      }
      __syncthreads();
      accx0 = (f32x4){}; accx1 = (f32x4){};
      X_MFMA(accx0, accx1);
    }
  }
#undef X_MFMA
}

// ---------------------------------------------------------------------------
__global__ __launch_bounds__(256) void fc_head(
    const f16* __restrict__ l2out,   // [B][512]
    const float* __restrict__ fc1_w, const float* __restrict__ fc1_b,
    const float* __restrict__ fc2_w, const float* __restrict__ fc2_b,
    const float* __restrict__ fc3_w, const float* __restrict__ fc3_b,
    float* __restrict__ out)
{
  __shared__ float last[512];
  __shared__ float h1[256];
  __shared__ float h2[128];
  const int b = blockIdx.x;
  const int t = threadIdx.x;
  for (int i = t; i < 512; i += 256)
    last[i] = (float)l2out[(size_t)b * 512 + i];
  __syncthreads();
  {
    float a = fc1_b[t];
    for (int k = 0; k < 512; ++k) a = fmaf(last[k], fc1_w[t * 512 + k], a);
    h1[t] = fmaxf(a, 0.f);
  }
  __syncthreads();
  if (t < 128) {
    float a = fc2_b[t];
    for (int k = 0; k < 256; ++k) a = fmaf(h1[k], fc2_w[t * 256 + k], a);
    h2[t] = fmaxf(a, 0.f);
  }
  __syncthreads();
  if (t == 0) {
    float a = fc3_b[0];
    for (int k = 0; k < 128; ++k) a = fmaf(h2[k], fc3_w[k], a);
    out[b] = a;
  }
}

__global__ void sentinel(float* out, int n, float v) {
  const int i = blockIdx.x * blockDim.x + threadIdx.x;
  if (i < n) out[i] = v;
}

// ---------------------------------------------------------------------------
extern "C" void kernel_launch(void* const* d_in, const int* in_sizes, int n_in,
                              void* d_out, int out_size, void* d_ws, size_t ws_size,
                              hipStream_t stream) {
  (void)in_sizes; (void)n_in;
  const float* x      = (const float*)d_in[0];
  const float* w_ih0  = (const float*)d_in[1];
  const float* w_hh0  = (const float*)d_in[2];
  const float* b0     = (const float*)d_in[3];
  const float* w_ih_r = (const float*)d_in[4];
  const float* w_hh_r = (const float*)d_in[5];
  const float* b_r    = (const float*)d_in[6];
  const float* fc1_w  = (const float*)d_in[7];
  const float* fc1_b  = (const float*)d_in[8];
  const float* fc2_w  = (const float*)d_in[9];
  const float* fc2_b  = (const float*)d_in[10];
  const float* fc3_w  = (const float*)d_in[11];
  const float* fc3_b  = (const float*)d_in[12];
  float* out = (float*)d_out;

  // ---- workspace carve (bytes) ----
  const size_t off_hA    = 0;
  const size_t off_aux   = off_hA    + (size_t)512*256*512*2;      // 128 MiB
  const size_t off_xT    = off_aux   + (size_t)2*256*256*256*2;    // +64 MiB
  const size_t off_l2o   = off_xT    + (size_t)512*256*64*2;       // +16 MiB
  const size_t off_exch  = off_l2o   + (size_t)256*512*2;          // +0.25 MiB
  const size_t off_exchF = off_exch  + (size_t)2*2*256*128*8;      // +1 MiB
  const size_t off_xprog = off_exchF + (size_t)2*2*256*128*8;      // +1 MiB
  const size_t need      = off_xprog + 1024;
  if (ws_size < need) {
    sentinel<<<1, 256, 0, stream>>>(out, out_size, (float)(ws_size >> 20));
    return;
  }
  char* ws = (char*)d_ws;
  f16* hA    = (f16*)(ws + off_hA);
  f16* aux   = (f16*)(ws + off_aux);
  f16* xT    = (f16*)(ws + off_xT);
  f16* l2out = (f16*)(ws + off_l2o);
  u64* exch  = (u64*)(ws + off_exch);
  u64* exchF = (u64*)(ws + off_exchF);
  u32* xprog = (u32*)(ws + off_xprog);

  // kill stale tags / MAGIC from previous replays (0xAA aliases no (L,s) tag)
  hipMemsetAsync(ws + off_exch, 0xAA, (size_t)2*2*256*128*8*2 + 1024, stream);

  transpose_x<<<512, 256, 0, stream>>>(x, xT);

  lstm_layer<0, 64><<<256, 256, 0, stream>>>(
      xT, hA, aux, l2out, exch, exchF, xprog, w_ih0, w_hh0, b0);
  lstm_layer<1, 512><<<256, 256, 0, stream>>>(
      xT, hA, aux, l2out, exch, exchF, xprog, w_ih_r, w_hh_r, b_r);
  lstm_layer<2, 512><<<256, 256, 0, stream>>>(
      xT, hA, aux, l2out, exch, exchF, xprog,
      w_ih_r + (size_t)2 * 1024 * 512, w_hh_r + (size_t)2 * 1024 * 256,
      b_r + 2048);

  fc_head<<<B_, 256, 0, stream>>>(l2out, fc1_w, fc1_b, fc2_w, fc2_b, fc3_w, fc3_b, out);
}

// Round 13
// 5165.891 us; speedup vs baseline: 1.1943x; 1.1943x over previous
//
#include <hip/hip_runtime.h>
#include <cstdint>
#include <cstddef>

#define B_ 256
#define S_ 512

typedef _Float16 f16;
typedef _Float16 f16x8 __attribute__((ext_vector_type(8)));
typedef _Float16 f16x4 __attribute__((ext_vector_type(4)));
typedef float f32x4 __attribute__((ext_vector_type(4)));
using u32 = unsigned int;
using u16 = unsigned short;
using u64 = unsigned long long;

#define TAGX   0x555u
#define MAGIC_ 0x13579BDFu

__device__ __forceinline__ float sigf(float x) { return 1.f / (1.f + __expf(-x)); }
__device__ __forceinline__ float tanh_f(float x) {
  x = fminf(15.f, fmaxf(-15.f, x));
  const float e = __expf(-2.f * x);
  return (1.f - e) / (1.f + e);
}
__device__ __forceinline__ f16x8 cvt_f16x8(float4 a, float4 b) {
  f16x8 t;
  t[0] = (f16)a.x; t[1] = (f16)a.y; t[2] = (f16)a.z; t[3] = (f16)a.w;
  t[4] = (f16)b.x; t[5] = (f16)b.y; t[6] = (f16)b.z; t[7] = (f16)b.w;
  return t;
}

// ---------------------------------------------------------------------------
// x transpose+convert: x[b][t][64] fp32 -> xT[t][b][64] f16
// ---------------------------------------------------------------------------
__global__ __launch_bounds__(256) void transpose_x(
    const float* __restrict__ x, f16* __restrict__ xT)
{
  const int t = blockIdx.x;
  const int col = threadIdx.x & 63;
  const int r0 = threadIdx.x >> 6;
  for (int it = 0; it < 64; ++it) {
    const int row = (it << 2) + r0;
    xT[((size_t)t * 256 + row) * 64 + col] =
        (f16)x[((size_t)row * S_ + t) * 64 + col];
  }
}

// ---------------------------------------------------------------------------
// Persistent fused BiLSTM layer (r7 geometry: 256 wgs = 1/CU, 256 thr).
// wg = dir*128 + bg*8 + sl : 16 batch rows x 32 h-units (128 gate cols).
// Weights in registers (W_ih f16; W_hh f16 hi + lo*2^10). h exchanged via
// tagged-f32 parity ring (sc1 RELAXED, 11-bit step tag in low mantissa,
// r7-proven). NEW vs r7: the x-part A-fragments are loaded DIRECTLY into
// per-lane registers (coalesced, matches MFMA A layout) -- x never touches
// LDS; one syncthreads and all x ds_reads removed from the step.
// ---------------------------------------------------------------------------
template<int L, int KIN>
__global__ __launch_bounds__(256, 1) void lstm_layer(
    const f16* __restrict__ xT,     // [512][256][64]   (L0 input)
    f16* __restrict__ hA,           // [512][256][512]
    f16* __restrict__ aux,          // [2][256][256][256]
    f16* __restrict__ l2out,        // [256][512]
    u64* __restrict__ exch,         // tagged ring [2 par][2 dir][256 b][128]
    u32* __restrict__ xprog,        // [2][128]
    const float* __restrict__ w_ih, // [2][1024][KIN]
    const float* __restrict__ w_hh, // [2][1024][256]
    const float* __restrict__ bias) // [2][1024]
{
  constexpr int NKT = KIN / 32;             // x K-tiles (A-frags per lane)
  __shared__ __align__(16) f16 h_s[16 * 256];
  __shared__ float gates_s[64 * 33];
  __shared__ char pad_[81920];              // force 1 wg/CU

  const int tid = threadIdx.x;
  const int lane = tid & 63, w = tid >> 6;
  const int l15 = lane & 15, l4 = lane >> 4;
  const int phys = blockIdx.x;
  const int wg = ((phys & 7) << 5) | (phys >> 3);  // co-locate groups per XCD
  const int dirv = wg >> 7, bg = (wg >> 3) & 15, sl = wg & 7;
  if ((int)blockIdx.x == -1) pad_[tid] = 0;

  // ---- weight slices -> registers ----
  f16x8 bih[2][NKT];
  f16x8 bhhH[2][8], bhhL[2][8];
#pragma unroll
  for (int nt = 0; nt < 2; ++nt) {
    const int grow = (w << 8) + (sl << 5) + (nt << 4) + l15;
    const float* pih = w_ih + ((size_t)(dirv << 10) + grow) * KIN + (l4 << 3);
#pragma unroll
    for (int kt = 0; kt < NKT; ++kt) {
      const float* p = pih + (kt << 5);
      bih[nt][kt] = cvt_f16x8(*(const float4*)p, *(const float4*)(p + 4));
    }
    const float* phh = w_hh + ((size_t)(dirv << 10) + grow) * 256 + (l4 << 3);
#pragma unroll
    for (int kt = 0; kt < 8; ++kt) {
      const float* p = phh + (kt << 5);
      float wf[8];
      *(float4*)&wf[0] = *(const float4*)p;
      *(float4*)&wf[4] = *(const float4*)(p + 4);
      f16x8 hi, lo;
#pragma unroll
      for (int j = 0; j < 8; ++j) {
        hi[j] = (f16)wf[j];
        lo[j] = (f16)((wf[j] - (float)hi[j]) * 1024.f);
      }
      bhhH[nt][kt] = hi;
      bhhL[nt][kt] = lo;
    }
  }

  const int crow = tid >> 4;
  const int u0 = (tid & 15) << 1;
  float bv[4][2];
#pragma unroll
  for (int g = 0; g < 4; ++g)
#pragma unroll
    for (int j = 0; j < 2; ++j)
      bv[g][j] = bias[(dirv << 10) + (g << 8) + (sl << 5) + u0 + j];
  float cs0 = 0.f, cs1 = 0.f;

  // ---- per-lane x A-fragment source: row = bg*16 + l15, granule kt*4+l4 ---
  const int arow = (bg << 4) + l15;
  auto xfrag_ld = [&](int t, int kt) -> f16x8 {
    const int g = (kt << 2) + l4;           // granule (8 f16) in the row
    if constexpr (L == 0) {
      return *(const f16x8*)(xT + ((size_t)t * 256 + arow) * 64 + (g << 3));
    } else if constexpr (L == 1) {
      return *(const f16x8*)(hA + ((size_t)t * 256 + arow) * 512 + (g << 3));
    } else {
      const int c0 = g << 3;
      const f16* p;
      if (c0 < 256)
        p = (t < 256) ? aux + ((size_t)t * 256 + arow) * 256 + c0
                      : hA + ((size_t)t * 256 + arow) * 512 + c0;
      else {
        const int u = c0 - 256;
        p = (t >= 256) ? aux + ((size_t)(256 + (511 - t)) * 256 + arow) * 256 + u
                       : hA + ((size_t)t * 256 + arow) * 512 + 256 + u;
      }
      return *(const f16x8*)p;
    }
  };

  f16x8 xfrag[NKT];

#define X_MFMA(A0, A1)                                                         \
  {                                                                            \
    _Pragma("unroll")                                                          \
    for (int kt = 0; kt < NKT; ++kt) {                                         \
      A0 = __builtin_amdgcn_mfma_f32_16x16x32_f16(xfrag[kt], bih[0][kt], A0, 0, 0, 0); \
      A1 = __builtin_amdgcn_mfma_f32_16x16x32_f16(xfrag[kt], bih[1][kt], A1, 0, 0, 0); \
    }                                                                          \
  }

  // ---- prologue: load x-frags for step 0, compute x-part ----
  {
    const int t0 = dirv ? (S_ - 1) : 0;
#pragma unroll
    for (int kt = 0; kt < NKT; ++kt) xfrag[kt] = xfrag_ld(t0, kt);
  }
  f32x4 accx0 = {}, accx1 = {};
  X_MFMA(accx0, accx1);

  for (int s = 0; s < S_; ++s) {
    const int t_or = dirv ? (S_ - 1 - s) : s;
    const bool pf = (s + 1 < S_);

    // ---- issue x-frag loads for step s+1 (in flight through the step) ----
    if (pf) {
      const int t_nx = dirv ? (t_or - 1) : (t_or + 1);
#pragma unroll
      for (int kt = 0; kt < NKT; ++kt) xfrag[kt] = xfrag_ld(t_nx, kt);
    }

    // ---- L1 crossover gate ----
    if constexpr (L == 1) {
      if (s == 256) {
        if (tid < 128) {
          const u32* pw = xprog + (1 - dirv) * 128 + tid;
          while (__hip_atomic_load(pw, __ATOMIC_RELAXED, __HIP_MEMORY_SCOPE_AGENT) != MAGIC_)
            __builtin_amdgcn_s_sleep(2);
        }
        __syncthreads();
      }
    }

    // ---- stage h(s-1) via tagged exch (r7-proven poll) ----
    if (s > 0) {
      const u32 tagp = ((u32)(L * 512 + s - 1) ^ TAGX) & 0x7FFu;
      const size_t ebase = ((size_t)(((s - 1) & 1) * 2 + dirv)) * 256 * 128;
      u32 vv[4][4];
      for (;;) {
        bool ok = true;
#pragma unroll
        for (int i = 0; i < 4; ++i) {
          const int G = tid + (i << 8);
          const int row = G >> 6, gr = G & 63;
          const u64* p = exch + ebase + ((bg << 4) + row) * 128 + (gr << 1);
          const u64 a = __hip_atomic_load(p, __ATOMIC_RELAXED, __HIP_MEMORY_SCOPE_AGENT);
          const u64 c = __hip_atomic_load(p + 1, __ATOMIC_RELAXED, __HIP_MEMORY_SCOPE_AGENT);
          vv[i][0] = (u32)a; vv[i][1] = (u32)(a >> 32);
          vv[i][2] = (u32)c; vv[i][3] = (u32)(c >> 32);
#pragma unroll
          for (int j = 0; j < 4; ++j) ok &= ((vv[i][j] & 0x7FFu) == tagp);
        }
        if (ok) break;
        __builtin_amdgcn_s_sleep(1);
      }
#pragma unroll
      for (int i = 0; i < 4; ++i) {
        const int G = tid + (i << 8);
        const int row = G >> 6, gr = G & 63;
        const int g8 = gr >> 1, half = gr & 1;
        f16x4 hh;
#pragma unroll
        for (int j = 0; j < 4; ++j)
          hh[j] = (f16)__builtin_bit_cast(float, vv[i][j] & 0xFFFFF800u);
        *(f16x4*)&h_s[(row << 8) + ((g8 ^ (row & 7)) << 3) + (half << 2)] = hh;
      }
    }
    __syncthreads();                               // h_s staged

    // ---- MFMAs: acc = accx + h@WhhHi + (h@WhhLo)/1024 ----
    f32x4 acc0 = accx0, acc1 = accx1;
    if (s > 0) {
      f32x4 aL0 = {}, aL1 = {};
#pragma unroll
      for (int kt = 0; kt < 8; ++kt) {
        const int gg = ((kt << 2) + l4) ^ (l15 & 7);
        const f16x8 a = *(const f16x8*)&h_s[(l15 << 8) + (gg << 3)];
        acc0 = __builtin_amdgcn_mfma_f32_16x16x32_f16(a, bhhH[0][kt], acc0, 0, 0, 0);
        acc1 = __builtin_amdgcn_mfma_f32_16x16x32_f16(a, bhhH[1][kt], acc1, 0, 0, 0);
        aL0 = __builtin_amdgcn_mfma_f32_16x16x32_f16(a, bhhL[0][kt], aL0, 0, 0, 0);
        aL1 = __builtin_amdgcn_mfma_f32_16x16x32_f16(a, bhhL[1][kt], aL1, 0, 0, 0);
      }
      acc0 += aL0 * (1.f / 1024.f);
      acc1 += aL1 * (1.f / 1024.f);
    }

    // ---- gate preacts -> LDS ----
#pragma unroll
    for (int r = 0; r < 4; ++r) {
      const int row = (l4 << 2) + r;
      gates_s[((w << 4) + row) * 33 + l15] = acc0[r];
      gates_s[((w << 4) + row) * 33 + 16 + l15] = acc1[r];
    }
    __syncthreads();

    // ---- cell update ----
    float hv[2];
    {
      float css[2] = { cs0, cs1 };
#pragma unroll
      for (int j = 0; j < 2; ++j) {
        const int u = u0 + j;
        const float gi = gates_s[(0 * 16 + crow) * 33 + u] + bv[0][j];
        const float gf = gates_s[(1 * 16 + crow) * 33 + u] + bv[1][j];
        const float gg = gates_s[(2 * 16 + crow) * 33 + u] + bv[2][j];
        const float go = gates_s[(3 * 16 + crow) * 33 + u] + bv[3][j];
        float cc = sigf(gf) * css[j] + sigf(gi) * tanh_f(gg);
        css[j] = cc;
        hv[j] = sigf(go) * tanh_f(cc);
      }
      cs0 = css[0]; cs1 = css[1];
    }

    // ---- publish h(s) (tagged exch first), then bulk stores ----
    // L1 in-place hazard: secure this step's xfrag loads before the de-facto
    // progress post (peers overwrite hA slab t_nx once all of s is posted).
    if (L == 1 && s >= 253) asm volatile("s_waitcnt vmcnt(0)" ::: "memory");
    {
      const u32 tagc = ((u32)(L * 512 + s) ^ TAGX) & 0x7FFu;
      const u32 w0 = ((__builtin_bit_cast(u32, hv[0]) + 0x400u) & 0xFFFFF800u) | tagc;
      const u32 w1 = ((__builtin_bit_cast(u32, hv[1]) + 0x400u) & 0xFFFFF800u) | tagc;
      const u64 pk = (u64)w0 | ((u64)w1 << 32);
      const int b = (bg << 4) + crow;
      const size_t eidx = ((size_t)((s & 1) * 2 + dirv)) * 256 * 128 + b * 128 + (sl << 4) + (u0 >> 1);
      __hip_atomic_store(exch + eidx, pk, __ATOMIC_RELAXED, __HIP_MEMORY_SCOPE_AGENT);

      union { u16 hw[2]; u32 pkh; } uh;
      uh.hw[0] = __builtin_bit_cast(u16, (f16)hv[0]);
      uh.hw[1] = __builtin_bit_cast(u16, (f16)hv[1]);
      const int uoff = (dirv << 7) + (sl << 4) + (u0 >> 1);
      if constexpr (L == 0) {
        ((u32*)hA)[((size_t)t_or * 256 + b) * 256 + uoff] = uh.pkh;
      } else if constexpr (L == 1) {
        if (s < 256)
          ((u32*)aux)[((size_t)(dirv * 256 + s) * 256 + b) * 128 + (sl << 4) + (u0 >> 1)] = uh.pkh;
        else
          ((u32*)hA)[((size_t)t_or * 256 + b) * 256 + uoff] = uh.pkh;
      } else {
        if (t_or == S_ - 1)
          ((u32*)l2out)[(size_t)b * 256 + uoff] = uh.pkh;
      }
    }

    // ---- L1: crossover MAGIC after h(254) globally posted ----
    if constexpr (L == 1) {
      if (s == 254) {
        asm volatile("s_waitcnt vmcnt(0)" ::: "memory");
        __syncthreads();
        if (tid == 0)
          __hip_atomic_store(xprog + dirv * 128 + (bg << 3) + sl, MAGIC_,
                             __ATOMIC_RELAXED, __HIP_MEMORY_SCOPE_AGENT);
      }
    }

    // ---- pre-compute x-part for s+1 from register frags (no LDS) ----
    if (pf) {
      accx0 = (f32x4){}; accx1 = (f32x4){};
      X_MFMA(accx0, accx1);
    }
  }
#undef X_MFMA
}

// ---------------------------------------------------------------------------
__global__ __launch_bounds__(256) void fc_head(
    const f16* __restrict__ l2out,   // [B][512]
    const float* __restrict__ fc1_w, const float* __restrict__ fc1_b,
    const float* __restrict__ fc2_w, const float* __restrict__ fc2_b,
    const float* __restrict__ fc3_w, const float* __restrict__ fc3_b,
    float* __restrict__ out)
{
  __shared__ float last[512];
  __shared__ float h1[256];
  __shared__ float h2[128];
  const int b = blockIdx.x;
  const int t = threadIdx.x;
  for (int i = t; i < 512; i += 256)
    last[i] = (float)l2out[(size_t)b * 512 + i];
  __syncthreads();
  {
    float a = fc1_b[t];
    for (int k = 0; k < 512; ++k) a = fmaf(last[k], fc1_w[t * 512 + k], a);
    h1[t] = fmaxf(a, 0.f);
  }
  __syncthreads();
  if (t < 128) {
    float a = fc2_b[t];
    for (int k = 0; k < 256; ++k) a = fmaf(h1[k], fc2_w[t * 256 + k], a);
    h2[t] = fmaxf(a, 0.f);
  }
  __syncthreads();
  if (t == 0) {
    float a = fc3_b[0];
    for (int k = 0; k < 128; ++k) a = fmaf(h2[k], fc3_w[k], a);
    out[b] = a;
  }
}

__global__ void sentinel(float* out, int n, float v) {
  const int i = blockIdx.x * blockDim.x + threadIdx.x;
  if (i < n) out[i] = v;
}

// ---------------------------------------------------------------------------
extern "C" void kernel_launch(void* const* d_in, const int* in_sizes, int n_in,
                              void* d_out, int out_size, void* d_ws, size_t ws_size,
                              hipStream_t stream) {
  (void)in_sizes; (void)n_in;
  const float* x      = (const float*)d_in[0];
  const float* w_ih0  = (const float*)d_in[1];
  const float* w_hh0  = (const float*)d_in[2];
  const float* b0     = (const float*)d_in[3];
  const float* w_ih_r = (const float*)d_in[4];
  const float* w_hh_r = (const float*)d_in[5];
  const float* b_r    = (const float*)d_in[6];
  const float* fc1_w  = (const float*)d_in[7];
  const float* fc1_b  = (const float*)d_in[8];
  const float* fc2_w  = (const float*)d_in[9];
  const float* fc2_b  = (const float*)d_in[10];
  const float* fc3_w  = (const float*)d_in[11];
  const float* fc3_b  = (const float*)d_in[12];
  float* out = (float*)d_out;

  // ---- workspace carve (bytes) ----
  const size_t off_hA    = 0;
  const size_t off_aux   = off_hA    + (size_t)512*256*512*2;      // 128 MiB
  const size_t off_xT    = off_aux   + (size_t)2*256*256*256*2;    // +64 MiB
  const size_t off_l2o   = off_xT    + (size_t)512*256*64*2;       // +16 MiB
  const size_t off_exch  = off_l2o   + (size_t)256*512*2;          // +0.25 MiB
  const size_t off_xprog = off_exch  + (size_t)2*2*256*128*8;      // +1 MiB
  const size_t need      = off_xprog + 1024;
  if (ws_size < need) {
    sentinel<<<1, 256, 0, stream>>>(out, out_size, (float)(ws_size >> 20));
    return;
  }
  char* ws = (char*)d_ws;
  f16* hA    = (f16*)(ws + off_hA);
  f16* aux   = (f16*)(ws + off_aux);
  f16* xT    = (f16*)(ws + off_xT);
  f16* l2out = (f16*)(ws + off_l2o);
  u64* exch  = (u64*)(ws + off_exch);
  u32* xprog = (u32*)(ws + off_xprog);

  // kill stale tags / MAGIC from previous replays (0xAA aliases no (L,s) tag)
  hipMemsetAsync(ws + off_exch, 0xAA, (size_t)2*2*256*128*8 + 1024, stream);

  transpose_x<<<512, 256, 0, stream>>>(x, xT);

  lstm_layer<0, 64><<<256, 256, 0, stream>>>(
      xT, hA, aux, l2out, exch, xprog, w_ih0, w_hh0, b0);
  lstm_layer<1, 512><<<256, 256, 0, stream>>>(
      xT, hA, aux, l2out, exch, xprog, w_ih_r, w_hh_r, b_r);
  lstm_layer<2, 512><<<256, 256, 0, stream>>>(
      xT, hA, aux, l2out, exch, xprog,
      w_ih_r + (size_t)2 * 1024 * 512, w_hh_r + (size_t)2 * 1024 * 256,
      b_r + 2048);

  fc_head<<<B_, 256, 0, stream>>>(l2out, fc1_w, fc1_b, fc2_w, fc2_b, fc3_w, fc3_b, out);
}

// Round 14
// 5117.932 us; speedup vs baseline: 1.2055x; 1.0094x over previous
//
#include <hip/hip_runtime.h>
#include <cstdint>
#include <cstddef>

#define B_ 256
#define S_ 512

typedef _Float16 f16;
typedef _Float16 f16x8 __attribute__((ext_vector_type(8)));
typedef _Float16 f16x4 __attribute__((ext_vector_type(4)));
typedef float f32x4 __attribute__((ext_vector_type(4)));
using u32 = unsigned int;
using u16 = unsigned short;
using u64 = unsigned long long;

#define TAGX   0x555u
#define MAGIC_ 0x13579BDFu

__device__ __forceinline__ float sigf(float x) { return 1.f / (1.f + __expf(-x)); }
__device__ __forceinline__ float tanh_f(float x) {
  x = fminf(15.f, fmaxf(-15.f, x));
  const float e = __expf(-2.f * x);
  return (1.f - e) / (1.f + e);
}
__device__ __forceinline__ f16x8 cvt_f16x8(float4 a, float4 b) {
  f16x8 t;
  t[0] = (f16)a.x; t[1] = (f16)a.y; t[2] = (f16)a.z; t[3] = (f16)a.w;
  t[4] = (f16)b.x; t[5] = (f16)b.y; t[6] = (f16)b.z; t[7] = (f16)b.w;
  return t;
}

// ---------------------------------------------------------------------------
// x transpose+convert: x[b][t][64] fp32 -> xT[t][b][64] f16
// ---------------------------------------------------------------------------
__global__ __launch_bounds__(256) void transpose_x(
    const float* __restrict__ x, f16* __restrict__ xT)
{
  const int t = blockIdx.x;
  const int col = threadIdx.x & 63;
  const int r0 = threadIdx.x >> 6;
  for (int it = 0; it < 64; ++it) {
    const int row = (it << 2) + r0;
    xT[((size_t)t * 256 + row) * 64 + col] =
        (f16)x[((size_t)row * S_ + t) * 64 + col];
  }
}

// ---------------------------------------------------------------------------
// Persistent fused BiLSTM layer (r7 base: 256 wgs = 1/CU, 256 thr, tagged-f32
// parity-ring exchange, sc1 RELAXED, step tag in low 11 mantissa bits).
// NEW vs r7: gate-interleaved wave mapping -- each wave owns ALL 4 gates for
// 8 units (nt0={i,f}, nt1={g,o}; lane l15 and l15^8 hold complementary gates
// of the SAME unit). Cell update via 2x shfl_xor(8) per row: the gates LDS
// buffer and one full-wg barrier per step are eliminated; waves publish
// independently as soon as their own MFMAs finish.
// ---------------------------------------------------------------------------
template<int L, int KIN>
__global__ __launch_bounds__(256, 1) void lstm_layer(
    const f16* __restrict__ xT,     // [512][256][64]   (L0 input)
    f16* __restrict__ hA,           // [512][256][512]
    f16* __restrict__ aux,          // [2][256][256][256]
    f16* __restrict__ l2out,        // [256][512]
    u64* __restrict__ exch,         // tagged ring [2 par][2 dir][256 b][128]
    u32* __restrict__ xprog,        // [2][128]
    const float* __restrict__ w_ih, // [2][1024][KIN]
    const float* __restrict__ w_hh, // [2][1024][256]
    const float* __restrict__ bias) // [2][1024]
{
  constexpr int GPR = KIN / 8;
  constexpr int LG  = (KIN == 512) ? 6 : 3;
  constexpr int NG  = 16 * GPR;
  constexpr int XI  = (NG + 255) / 256;
  __shared__ __align__(16) f16 x_s[16 * KIN];
  __shared__ __align__(16) f16 h_s[16 * 256];
  __shared__ char pad_[81920];              // force 1 wg/CU

  const int tid = threadIdx.x;
  const int lane = tid & 63, w = tid >> 6;
  const int l15 = lane & 15, l4 = lane >> 4;
  const int phys = blockIdx.x;
  const int wg = ((phys & 7) << 5) | (phys >> 3);  // co-locate groups per XCD
  const int dirv = wg >> 7, bg = (wg >> 3) & 15, sl = wg & 7;
  if ((int)blockIdx.x == -1) pad_[tid] = 0;

  // ---- weight slices -> registers (gate-interleaved mapping) ----
  // nt tile col l15 -> gate g = nt*2 + (l15>>3), unit u = w*8 + (l15&7)
  f16x8 bih[2][KIN / 32];
  f16x8 bhhH[2][8], bhhL[2][8];
  float bv[2];
#pragma unroll
  for (int nt = 0; nt < 2; ++nt) {
    const int g_gate = (nt << 1) + (l15 >> 3);
    const int grow = (g_gate << 8) + (sl << 5) + (w << 3) + (l15 & 7);
    bv[nt] = bias[(dirv << 10) + grow];
    const float* pih = w_ih + ((size_t)(dirv << 10) + grow) * KIN + (l4 << 3);
#pragma unroll
    for (int kt = 0; kt < KIN / 32; ++kt) {
      const float* p = pih + (kt << 5);
      bih[nt][kt] = cvt_f16x8(*(const float4*)p, *(const float4*)(p + 4));
    }
    const float* phh = w_hh + ((size_t)(dirv << 10) + grow) * 256 + (l4 << 3);
#pragma unroll
    for (int kt = 0; kt < 8; ++kt) {
      const float* p = phh + (kt << 5);
      float wf[8];
      *(float4*)&wf[0] = *(const float4*)p;
      *(float4*)&wf[4] = *(const float4*)(p + 4);
      f16x8 hi, lo;
#pragma unroll
      for (int j = 0; j < 8; ++j) {
        hi[j] = (f16)wf[j];
        lo[j] = (f16)((wf[j] - (float)hi[j]) * 1024.f);
      }
      bhhH[nt][kt] = hi;
      bhhL[nt][kt] = lo;
    }
  }

  // per-thread cell state: unit u = w*8+(l15&7), rows l4*4+r (redundant x2
  // across the l15^8 lane pair)
  float cs[4] = {0.f, 0.f, 0.f, 0.f};

  auto xsrc = [&](int t, int b, int g) -> const f16* {
    if constexpr (L == 0) {
      return xT + ((size_t)t * 256 + b) * 64 + (g << 3);
    } else if constexpr (L == 1) {
      return hA + ((size_t)t * 256 + b) * 512 + (g << 3);
    } else {
      const int c0 = g << 3;
      if (c0 < 256)
        return (t < 256) ? aux + ((size_t)t * 256 + b) * 256 + c0
                         : hA + ((size_t)t * 256 + b) * 512 + c0;
      const int u = c0 - 256;
      return (t >= 256) ? aux + ((size_t)(256 + (511 - t)) * 256 + b) * 256 + u
                        : hA + ((size_t)t * 256 + b) * 512 + 256 + u;
    }
  };

#define X_MFMA(A0, A1)                                                         \
  {                                                                            \
    _Pragma("unroll")                                                          \
    for (int kt = 0; kt < KIN / 32; ++kt) {                                    \
      const int gg = ((kt << 2) + l4) ^ (l15 & 7);                             \
      const f16x8 a = *(const f16x8*)&x_s[l15 * KIN + (gg << 3)];              \
      A0 = __builtin_amdgcn_mfma_f32_16x16x32_f16(a, bih[0][kt], A0, 0, 0, 0); \
      A1 = __builtin_amdgcn_mfma_f32_16x16x32_f16(a, bih[1][kt], A1, 0, 0, 0); \
    }                                                                          \
  }

  // ---- prologue: stage x(0), compute its x-part ----
  f16x8 xreg[XI];
  {
    const int t0 = dirv ? (S_ - 1) : 0;
#pragma unroll
    for (int i = 0; i < XI; ++i) {
      const int G = tid + (i << 8);
      if (NG < 256 && G >= NG) break;
      const int row = G >> LG, g = G & (GPR - 1);
      xreg[i] = *(const f16x8*)xsrc(t0, (bg << 4) + row, g);
    }
#pragma unroll
    for (int i = 0; i < XI; ++i) {
      const int G = tid + (i << 8);
      if (NG < 256 && G >= NG) break;
      const int row = G >> LG, g = G & (GPR - 1);
      *(f16x8*)&x_s[row * KIN + ((g ^ (row & 7)) << 3)] = xreg[i];
    }
  }
  __syncthreads();
  f32x4 accx0 = {}, accx1 = {};
  X_MFMA(accx0, accx1);

  for (int s = 0; s < S_; ++s) {
    const int t_or = dirv ? (S_ - 1 - s) : s;
    const bool pf = (s + 1 < S_);

    // ---- issue x prefetch for step s+1 ----
    if (pf) {
      const int t_nx = dirv ? (t_or - 1) : (t_or + 1);
#pragma unroll
      for (int i = 0; i < XI; ++i) {
        const int G = tid + (i << 8);
        if (NG < 256 && G >= NG) break;
        const int row = G >> LG, g = G & (GPR - 1);
        xreg[i] = *(const f16x8*)xsrc(t_nx, (bg << 4) + row, g);
      }
    }

    // ---- L1 crossover gate ----
    if constexpr (L == 1) {
      if (s == 256) {
        if (tid < 128) {
          const u32* pw = xprog + (1 - dirv) * 128 + tid;
          while (__hip_atomic_load(pw, __ATOMIC_RELAXED, __HIP_MEMORY_SCOPE_AGENT) != MAGIC_)
            __builtin_amdgcn_s_sleep(2);
        }
        __syncthreads();
      }
    }

    // ---- stage h(s-1) via tagged exch (r7-proven poll) ----
    if (s > 0) {
      const u32 tagp = ((u32)(L * 512 + s - 1) ^ TAGX) & 0x7FFu;
      const size_t ebase = ((size_t)(((s - 1) & 1) * 2 + dirv)) * 256 * 128;
      u32 vv[4][4];
      for (;;) {
        bool ok = true;
#pragma unroll
        for (int i = 0; i < 4; ++i) {
          const int G = tid + (i << 8);
          const int row = G >> 6, gr = G & 63;
          const u64* p = exch + ebase + ((bg << 4) + row) * 128 + (gr << 1);
          const u64 a = __hip_atomic_load(p, __ATOMIC_RELAXED, __HIP_MEMORY_SCOPE_AGENT);
          const u64 c = __hip_atomic_load(p + 1, __ATOMIC_RELAXED, __HIP_MEMORY_SCOPE_AGENT);
          vv[i][0] = (u32)a; vv[i][1] = (u32)(a >> 32);
          vv[i][2] = (u32)c; vv[i][3] = (u32)(c >> 32);
#pragma unroll
          for (int j = 0; j < 4; ++j) ok &= ((vv[i][j] & 0x7FFu) == tagp);
        }
        if (ok) break;
        __builtin_amdgcn_s_sleep(1);
      }
#pragma unroll
      for (int i = 0; i < 4; ++i) {
        const int G = tid + (i << 8);
        const int row = G >> 6, gr = G & 63;
        const int g8 = gr >> 1, half = gr & 1;
        f16x4 hh;
#pragma unroll
        for (int j = 0; j < 4; ++j)
          hh[j] = (f16)__builtin_bit_cast(float, vv[i][j] & 0xFFFFF800u);
        *(f16x4*)&h_s[(row << 8) + ((g8 ^ (row & 7)) << 3) + (half << 2)] = hh;
      }
    }
    __syncthreads();                               // h_s staged

    // ---- MFMAs: acc = accx + h@WhhHi + (h@WhhLo)/1024 ----
    f32x4 acc0 = accx0, acc1 = accx1;
    if (s > 0) {
      f32x4 aL0 = {}, aL1 = {};
#pragma unroll
      for (int kt = 0; kt < 8; ++kt) {
        const int gg = ((kt << 2) + l4) ^ (l15 & 7);
        const f16x8 a = *(const f16x8*)&h_s[(l15 << 8) + (gg << 3)];
        acc0 = __builtin_amdgcn_mfma_f32_16x16x32_f16(a, bhhH[0][kt], acc0, 0, 0, 0);
        acc1 = __builtin_amdgcn_mfma_f32_16x16x32_f16(a, bhhH[1][kt], acc1, 0, 0, 0);
        aL0 = __builtin_amdgcn_mfma_f32_16x16x32_f16(a, bhhL[0][kt], aL0, 0, 0, 0);
        aL1 = __builtin_amdgcn_mfma_f32_16x16x32_f16(a, bhhL[1][kt], aL1, 0, 0, 0);
      }
      acc0 += aL0 * (1.f / 1024.f);
      acc1 += aL1 * (1.f / 1024.f);
    }

    // ---- cell update via shfl (no gates LDS, no barrier) ----
    // acc0[r] = gate (l15<8 ? i : f), acc1[r] = gate (l15<8 ? g : o)
    // for unit u = w*8+(l15&7), row = l4*4+r. Pair l15^8 holds the rest.
    float hv[4];
    {
      const bool loH = (l15 < 8);
#pragma unroll
      for (int r = 0; r < 4; ++r) {
        const float a0 = acc0[r] + bv[0];
        const float a1 = acc1[r] + bv[1];
        const float o0 = __shfl_xor(a0, 8);
        const float o1 = __shfl_xor(a1, 8);
        const float gi = loH ? a0 : o0;
        const float gf = loH ? o0 : a0;
        const float gg = loH ? a1 : o1;
        const float go = loH ? o1 : a1;
        float cc = sigf(gf) * cs[r] + sigf(gi) * tanh_f(gg);
        cs[r] = cc;
        hv[r] = sigf(go) * tanh_f(cc);
      }
    }

    // ---- publish h(s) (tagged exch first), then bulk stores ----
    // L1 in-place hazard: secure this step's x loads before the de-facto
    // progress post (peers overwrite hA slab t_nx once all of s is posted).
    if (L == 1 && s >= 253) asm volatile("s_waitcnt vmcnt(0)" ::: "memory");
    {
      const u32 tagc = ((u32)(L * 512 + s) ^ TAGX) & 0x7FFu;
      const size_t pbase = ((size_t)((s & 1) * 2 + dirv)) * 256 * 128;
      const int p_g = (sl << 4) + (w << 2) + ((l15 & 7) >> 1);  // pair 0..127
      const bool evenL = ((l15 & 1) == 0);
      const int rhalf = (l15 >> 3) << 1;        // l15<8 -> rows 0,1 ; else 2,3
#pragma unroll
      for (int r = 0; r < 4; ++r) {
        const u32 tw = ((__builtin_bit_cast(u32, hv[r]) + 0x400u) & 0xFFFFF800u) | tagc;
        const u32 nb = __shfl_xor(tw, 1);
        const u32 h16 = (u32)__builtin_bit_cast(u16, (f16)hv[r]);
        const u32 nh = __shfl_xor(h16, 1);
        if (evenL && (r == rhalf || r == rhalf + 1)) {
          const u64 pk64 = (u64)tw | ((u64)nb << 32);
          const u32 pkh = h16 | (nh << 16);
          const int b = (bg << 4) + (l4 << 2) + r;
          __hip_atomic_store(exch + pbase + (size_t)b * 128 + p_g, pk64,
                             __ATOMIC_RELAXED, __HIP_MEMORY_SCOPE_AGENT);
          const int uoff = (dirv << 7) + p_g;
          if constexpr (L == 0) {
            ((u32*)hA)[((size_t)t_or * 256 + b) * 256 + uoff] = pkh;
          } else if constexpr (L == 1) {
            if (s < 256)
              ((u32*)aux)[((size_t)(dirv * 256 + s) * 256 + b) * 128 + p_g] = pkh;
            else
              ((u32*)hA)[((size_t)t_or * 256 + b) * 256 + uoff] = pkh;
          } else {
            if (t_or == S_ - 1)
              ((u32*)l2out)[(size_t)b * 256 + uoff] = pkh;
          }
        }
      }
    }

    // ---- L1: crossover MAGIC after h(254) globally posted ----
    if constexpr (L == 1) {
      if (s == 254) {
        asm volatile("s_waitcnt vmcnt(0)" ::: "memory");
        __syncthreads();
        if (tid == 0)
          __hip_atomic_store(xprog + dirv * 128 + (bg << 3) + sl, MAGIC_,
                             __ATOMIC_RELAXED, __HIP_MEMORY_SCOPE_AGENT);
      }
    }

    // ---- write x_s for s+1 and pre-compute its x-part ----
    if (pf) {
#pragma unroll
      for (int i = 0; i < XI; ++i) {
        const int G = tid + (i << 8);
        if (NG < 256 && G >= NG) break;
        const int row = G >> LG, g = G & (GPR - 1);
        *(f16x8*)&x_s[row * KIN + ((g ^ (row & 7)) << 3)] = xreg[i];
      }
      __syncthreads();
      accx0 = (f32x4){}; accx1 = (f32x4){};
      X_MFMA(accx0, accx1);
    }
  }
#undef X_MFMA
}

// ---------------------------------------------------------------------------
__global__ __launch_bounds__(256) void fc_head(
    const f16* __restrict__ l2out,   // [B][512]
    const float* __restrict__ fc1_w, const float* __restrict__ fc1_b,
    const float* __restrict__ fc2_w, const float* __restrict__ fc2_b,
    const float* __restrict__ fc3_w, const float* __restrict__ fc3_b,
    float* __restrict__ out)
{
  __shared__ float last[512];
  __shared__ float h1[256];
  __shared__ float h2[128];
  const int b = blockIdx.x;
  const int t = threadIdx.x;
  for (int i = t; i < 512; i += 256)
    last[i] = (float)l2out[(size_t)b * 512 + i];
  __syncthreads();
  {
    float a = fc1_b[t];
    for (int k = 0; k < 512; ++k) a = fmaf(last[k], fc1_w[t * 512 + k], a);
    h1[t] = fmaxf(a, 0.f);
  }
  __syncthreads();
  if (t < 128) {
    float a = fc2_b[t];
    for (int k = 0; k < 256; ++k) a = fmaf(h1[k], fc2_w[t * 256 + k], a);
    h2[t] = fmaxf(a, 0.f);
  }
  __syncthreads();
  if (t == 0) {
    float a = fc3_b[0];
    for (int k = 0; k < 128; ++k) a = fmaf(h2[k], fc3_w[k], a);
    out[b] = a;
  }
}

__global__ void sentinel(float* out, int n, float v) {
  const int i = blockIdx.x * blockDim.x + threadIdx.x;
  if (i < n) out[i] = v;
}

// ---------------------------------------------------------------------------
extern "C" void kernel_launch(void* const* d_in, const int* in_sizes, int n_in,
                              void* d_out, int out_size, void* d_ws, size_t ws_size,
                              hipStream_t stream) {
  (void)in_sizes; (void)n_in;
  const float* x      = (const float*)d_in[0];
  const float* w_ih0  = (const float*)d_in[1];
  const float* w_hh0  = (const float*)d_in[2];
  const float* b0     = (const float*)d_in[3];
  const float* w_ih_r = (const float*)d_in[4];
  const float* w_hh_r = (const float*)d_in[5];
  const float* b_r    = (const float*)d_in[6];
  const float* fc1_w  = (const float*)d_in[7];
  const float* fc1_b  = (const float*)d_in[8];
  const float* fc2_w  = (const float*)d_in[9];
  const float* fc2_b  = (const float*)d_in[10];
  const float* fc3_w  = (const float*)d_in[11];
  const float* fc3_b  = (const float*)d_in[12];
  float* out = (float*)d_out;

  // ---- workspace carve (bytes) ----
  const size_t off_hA    = 0;
  const size_t off_aux   = off_hA    + (size_t)512*256*512*2;      // 128 MiB
  const size_t off_xT    = off_aux   + (size_t)2*256*256*256*2;    // +64 MiB
  const size_t off_l2o   = off_xT    + (size_t)512*256*64*2;       // +16 MiB
  const size_t off_exch  = off_l2o   + (size_t)256*512*2;          // +0.25 MiB
  const size_t off_xprog = off_exch  + (size_t)2*2*256*128*8;      // +1 MiB
  const size_t need      = off_xprog + 1024;
  if (ws_size < need) {
    sentinel<<<1, 256, 0, stream>>>(out, out_size, (float)(ws_size >> 20));
    return;
  }
  char* ws = (char*)d_ws;
  f16* hA    = (f16*)(ws + off_hA);
  f16* aux   = (f16*)(ws + off_aux);
  f16* xT    = (f16*)(ws + off_xT);
  f16* l2out = (f16*)(ws + off_l2o);
  u64* exch  = (u64*)(ws + off_exch);
  u32* xprog = (u32*)(ws + off_xprog);

  // kill stale tags / MAGIC from previous replays (0xAA aliases no (L,s) tag)
  hipMemsetAsync(ws + off_exch, 0xAA, (size_t)2*2*256*128*8 + 1024, stream);

  transpose_x<<<512, 256, 0, stream>>>(x, xT);

  lstm_layer<0, 64><<<256, 256, 0, stream>>>(
      xT, hA, aux, l2out, exch, xprog, w_ih0, w_hh0, b0);
  lstm_layer<1, 512><<<256, 256, 0, stream>>>(
      xT, hA, aux, l2out, exch, xprog, w_ih_r, w_hh_r, b_r);
  lstm_layer<2, 512><<<256, 256, 0, stream>>>(
      xT, hA, aux, l2out, exch, xprog,
      w_ih_r + (size_t)2 * 1024 * 512, w_hh_r + (size_t)2 * 1024 * 256,
      b_r + 2048);

  fc_head<<<B_, 256, 0, stream>>>(l2out, fc1_w, fc1_b, fc2_w, fc2_b, fc3_w, fc3_b, out);
}

// Round 15
// 3851.595 us; speedup vs baseline: 1.6018x; 1.3288x over previous
//
#include <hip/hip_runtime.h>
#include <cstdint>
#include <cstddef>

#define B_ 256
#define S_ 512

typedef _Float16 f16;
typedef _Float16 f16x8 __attribute__((ext_vector_type(8)));
typedef _Float16 f16x4 __attribute__((ext_vector_type(4)));
typedef float f32x4 __attribute__((ext_vector_type(4)));
using u32 = unsigned int;
using u16 = unsigned short;
using u64 = unsigned long long;

#define TAGX   0x555u
#define MAGIC_ 0x13579BDFu

__device__ __forceinline__ float sigf(float x) { return 1.f / (1.f + __expf(-x)); }
__device__ __forceinline__ float tanh_f(float x) {
  x = fminf(15.f, fmaxf(-15.f, x));
  const float e = __expf(-2.f * x);
  return (1.f - e) / (1.f + e);
}
__device__ __forceinline__ f16x8 cvt_f16x8(float4 a, float4 b) {
  f16x8 t;
  t[0] = (f16)a.x; t[1] = (f16)a.y; t[2] = (f16)a.z; t[3] = (f16)a.w;
  t[4] = (f16)b.x; t[5] = (f16)b.y; t[6] = (f16)b.z; t[7] = (f16)b.w;
  return t;
}

// ---------------------------------------------------------------------------
// x transpose+convert: x[b][t][64] fp32 -> xT[t][b][64] f16  (t-major slabs)
// ---------------------------------------------------------------------------
__global__ __launch_bounds__(256) void transpose_x(
    const float* __restrict__ x, f16* __restrict__ xT)
{
  const int t = blockIdx.x;
  const int col = threadIdx.x & 63;
  const int r0 = threadIdx.x >> 6;
  for (int it = 0; it < 64; ++it) {
    const int row = (it << 2) + r0;
    xT[((size_t)t * 256 + row) * 64 + col] =
        (f16)x[((size_t)row * S_ + t) * 64 + col];
  }
}

// ---------------------------------------------------------------------------
// Persistent fused BiLSTM layer (plain launch, 256 wgs = 1/CU via LDS pad).
// wg = dir*128 + bg*8 + sl : 16 batch rows x 32 h-units (128 gate cols).
// Weights in registers (W_ih f16; W_hh hi/lo split). Exchange of h between
// the 8 wgs of a (dir,bg) group goes through a tagged-f32 parity-double-
// buffered exch ring: tag in low 11 mantissa bits self-validates freshness
// (single round trip, no flags, no fences). hA/aux/l2out use PLAIN stores
// (read-before-overwrite proven by the exch handshake; cross-launch
// visibility via kernel boundaries).
//   L=0: reads xT (K=64), writes hA[t][b][512].
//   L=1: reads hA, writes aux (s<256) / hA in-place (s>=256); one-time
//        fwd<->bwd crossover handshake at s==256 via xprog MAGIC words.
//   L=2: reads {hA,aux} composite, writes only the t=511 slab to l2out.
// This configuration is the measured local optimum (r7 = 3.84 ms); rounds
// 8-14 refuted: sc0 fast-path (±throttle), canary poll, 512-thr wgs (VGPR
// spill), 4-party groups, direct per-lane A-frags (4x redundant loads),
// shfl-based cell update. Step cost is exchange-visibility-RT-bound.
// ---------------------------------------------------------------------------
template<int L, int KIN>
__global__ __launch_bounds__(256, 1) void lstm_layer(
    const f16* __restrict__ xT,     // [512][256][64]   (L0 input)
    f16* __restrict__ hA,           // [512][256][512]
    f16* __restrict__ aux,          // [2][256][256][256]
    f16* __restrict__ l2out,        // [256][512]
    u64* __restrict__ exch,         // tagged ring [2 par][2 dir][256 b][128]
    u32* __restrict__ xprog,        // [2][128]
    const float* __restrict__ w_ih, // [2][1024][KIN]
    const float* __restrict__ w_hh, // [2][1024][256]
    const float* __restrict__ bias) // [2][1024]
{
  constexpr int GPR = KIN / 8;
  constexpr int LG  = (KIN == 512) ? 6 : 3;
  constexpr int NG  = 16 * GPR;
  constexpr int XI  = (NG + 255) / 256;
  __shared__ __align__(16) f16 x_s[16 * KIN];
  __shared__ __align__(16) f16 h_s[16 * 256];
  __shared__ float gates_s[64 * 33];
  __shared__ char pad_[81920];              // force 1 wg/CU

  const int tid = threadIdx.x;
  const int lane = tid & 63, w = tid >> 6;
  const int l15 = lane & 15, l4 = lane >> 4;
  const int phys = blockIdx.x;
  const int wg = ((phys & 7) << 5) | (phys >> 3);  // co-locate groups per XCD
  const int dirv = wg >> 7, bg = (wg >> 3) & 15, sl = wg & 7;
  if ((int)blockIdx.x == -1) pad_[tid] = 0;

  // ---- weight slices -> registers ----
  f16x8 bih[2][KIN / 32];
  f16x8 bhhH[2][8], bhhL[2][8];
#pragma unroll
  for (int nt = 0; nt < 2; ++nt) {
    const int grow = (w << 8) + (sl << 5) + (nt << 4) + l15;
    const float* pih = w_ih + ((size_t)(dirv << 10) + grow) * KIN + (l4 << 3);
#pragma unroll
    for (int kt = 0; kt < KIN / 32; ++kt) {
      const float* p = pih + (kt << 5);
      bih[nt][kt] = cvt_f16x8(*(const float4*)p, *(const float4*)(p + 4));
    }
    const float* phh = w_hh + ((size_t)(dirv << 10) + grow) * 256 + (l4 << 3);
#pragma unroll
    for (int kt = 0; kt < 8; ++kt) {
      const float* p = phh + (kt << 5);
      float wf[8];
      *(float4*)&wf[0] = *(const float4*)p;
      *(float4*)&wf[4] = *(const float4*)(p + 4);
      f16x8 hi, lo;
#pragma unroll
      for (int j = 0; j < 8; ++j) {
        hi[j] = (f16)wf[j];
        lo[j] = (f16)((wf[j] - (float)hi[j]) * 1024.f);
      }
      bhhH[nt][kt] = hi;
      bhhL[nt][kt] = lo;
    }
  }

  const int crow = tid >> 4;
  const int u0 = (tid & 15) << 1;
  float bv[4][2];
#pragma unroll
  for (int g = 0; g < 4; ++g)
#pragma unroll
    for (int j = 0; j < 2; ++j)
      bv[g][j] = bias[(dirv << 10) + (g << 8) + (sl << 5) + u0 + j];
  float cs0 = 0.f, cs1 = 0.f;

  auto xsrc = [&](int t, int b, int g) -> const f16* {
    if constexpr (L == 0) {
      return xT + ((size_t)t * 256 + b) * 64 + (g << 3);
    } else if constexpr (L == 1) {
      return hA + ((size_t)t * 256 + b) * 512 + (g << 3);
    } else {
      const int c0 = g << 3;
      if (c0 < 256)
        return (t < 256) ? aux + ((size_t)t * 256 + b) * 256 + c0
                         : hA + ((size_t)t * 256 + b) * 512 + c0;
      const int u = c0 - 256;
      return (t >= 256) ? aux + ((size_t)(256 + (511 - t)) * 256 + b) * 256 + u
                        : hA + ((size_t)t * 256 + b) * 512 + 256 + u;
    }
  };

#define X_MFMA(A0, A1)                                                         \
  {                                                                            \
    _Pragma("unroll")                                                          \
    for (int kt = 0; kt < KIN / 32; ++kt) {                                    \
      const int gg = ((kt << 2) + l4) ^ (l15 & 7);                             \
      const f16x8 a = *(const f16x8*)&x_s[l15 * KIN + (gg << 3)];              \
      A0 = __builtin_amdgcn_mfma_f32_16x16x32_f16(a, bih[0][kt], A0, 0, 0, 0); \
      A1 = __builtin_amdgcn_mfma_f32_16x16x32_f16(a, bih[1][kt], A1, 0, 0, 0); \
    }                                                                          \
  }

  // ---- prologue: stage x(0), compute its x-part ----
  f16x8 xreg[XI];
  {
    const int t0 = dirv ? (S_ - 1) : 0;
#pragma unroll
    for (int i = 0; i < XI; ++i) {
      const int G = tid + (i << 8);
      if (NG < 256 && G >= NG) break;
      const int row = G >> LG, g = G & (GPR - 1);
      xreg[i] = *(const f16x8*)xsrc(t0, (bg << 4) + row, g);
    }
#pragma unroll
    for (int i = 0; i < XI; ++i) {
      const int G = tid + (i << 8);
      if (NG < 256 && G >= NG) break;
      const int row = G >> LG, g = G & (GPR - 1);
      *(f16x8*)&x_s[row * KIN + ((g ^ (row & 7)) << 3)] = xreg[i];
    }
  }
  __syncthreads();
  f32x4 accx0 = {}, accx1 = {};
  X_MFMA(accx0, accx1);

  for (int s = 0; s < S_; ++s) {
    const int t_or = dirv ? (S_ - 1 - s) : s;
    const bool pf = (s + 1 < S_);

    // ---- issue x prefetch for step s+1 ----
    if (pf) {
      const int t_nx = dirv ? (t_or - 1) : (t_or + 1);
#pragma unroll
      for (int i = 0; i < XI; ++i) {
        const int G = tid + (i << 8);
        if (NG < 256 && G >= NG) break;
        const int row = G >> LG, g = G & (GPR - 1);
        xreg[i] = *(const f16x8*)xsrc(t_nx, (bg << 4) + row, g);
      }
    }

    // ---- L1 crossover gate ----
    if constexpr (L == 1) {
      if (s == 256) {
        if (tid < 128) {
          const u32* pw = xprog + (1 - dirv) * 128 + tid;
          while (__hip_atomic_load(pw, __ATOMIC_RELAXED, __HIP_MEMORY_SCOPE_AGENT) != MAGIC_)
            __builtin_amdgcn_s_sleep(2);
        }
        __syncthreads();
      }
    }

    // ---- stage h(s-1) via tagged exch (spin until all 16 tags fresh) ----
    if (s > 0) {
      const u32 tagp = ((u32)(L * 512 + s - 1) ^ TAGX) & 0x7FFu;
      const u64* ex = exch + ((size_t)(((s - 1) & 1) * 2 + dirv)) * 256 * 128;
      u32 vv[4][4];
      for (;;) {
        bool ok = true;
#pragma unroll
        for (int i = 0; i < 4; ++i) {
          const int G = tid + (i << 8);
          const int row = G >> 6, gr = G & 63;
          const int b = (bg << 4) + row;
          const u64* p = ex + b * 128 + (gr << 1);
          const u64 a = __hip_atomic_load(p, __ATOMIC_RELAXED, __HIP_MEMORY_SCOPE_AGENT);
          const u64 c = __hip_atomic_load(p + 1, __ATOMIC_RELAXED, __HIP_MEMORY_SCOPE_AGENT);
          vv[i][0] = (u32)a; vv[i][1] = (u32)(a >> 32);
          vv[i][2] = (u32)c; vv[i][3] = (u32)(c >> 32);
#pragma unroll
          for (int j = 0; j < 4; ++j) ok &= ((vv[i][j] & 0x7FFu) == tagp);
        }
        if (ok) break;
        __builtin_amdgcn_s_sleep(1);
      }
#pragma unroll
      for (int i = 0; i < 4; ++i) {
        const int G = tid + (i << 8);
        const int row = G >> 6, gr = G & 63;
        const int g8 = gr >> 1, half = gr & 1;
        f16x4 hh;
#pragma unroll
        for (int j = 0; j < 4; ++j)
          hh[j] = (f16)__builtin_bit_cast(float, vv[i][j] & 0xFFFFF800u);
        *(f16x4*)&h_s[(row << 8) + ((g8 ^ (row & 7)) << 3) + (half << 2)] = hh;
      }
    }
    __syncthreads();                               // h_s staged

    // ---- MFMAs: acc = accx + h@WhhHi + (h@WhhLo)/1024 ----
    f32x4 acc0 = accx0, acc1 = accx1;
    if (s > 0) {
      f32x4 aL0 = {}, aL1 = {};
#pragma unroll
      for (int kt = 0; kt < 8; ++kt) {
        const int gg = ((kt << 2) + l4) ^ (l15 & 7);
        const f16x8 a = *(const f16x8*)&h_s[(l15 << 8) + (gg << 3)];
        acc0 = __builtin_amdgcn_mfma_f32_16x16x32_f16(a, bhhH[0][kt], acc0, 0, 0, 0);
        acc1 = __builtin_amdgcn_mfma_f32_16x16x32_f16(a, bhhH[1][kt], acc1, 0, 0, 0);
        aL0 = __builtin_amdgcn_mfma_f32_16x16x32_f16(a, bhhL[0][kt], aL0, 0, 0, 0);
        aL1 = __builtin_amdgcn_mfma_f32_16x16x32_f16(a, bhhL[1][kt], aL1, 0, 0, 0);
      }
      acc0 += aL0 * (1.f / 1024.f);
      acc1 += aL1 * (1.f / 1024.f);
    }

    // ---- gate preacts -> LDS ----
#pragma unroll
    for (int r = 0; r < 4; ++r) {
      const int row = (l4 << 2) + r;
      gates_s[((w << 4) + row) * 33 + l15] = acc0[r];
      gates_s[((w << 4) + row) * 33 + 16 + l15] = acc1[r];
    }
    __syncthreads();

    // ---- cell update ----
    float hv[2];
    {
      float css[2] = { cs0, cs1 };
#pragma unroll
      for (int j = 0; j < 2; ++j) {
        const int u = u0 + j;
        const float gi = gates_s[(0 * 16 + crow) * 33 + u] + bv[0][j];
        const float gf = gates_s[(1 * 16 + crow) * 33 + u] + bv[1][j];
        const float gg = gates_s[(2 * 16 + crow) * 33 + u] + bv[2][j];
        const float go = gates_s[(3 * 16 + crow) * 33 + u] + bv[3][j];
        float cc = sigf(gf) * css[j] + sigf(gi) * tanh_f(gg);
        css[j] = cc;
        hv[j] = sigf(go) * tanh_f(cc);
      }
      cs0 = css[0]; cs1 = css[1];
    }

    // ---- publish h(s) (tagged exch first), then bulk stores ----
    if (L == 1 && s >= 253) asm volatile("s_waitcnt vmcnt(0)" ::: "memory");
    {
      const u32 tagc = ((u32)(L * 512 + s) ^ TAGX) & 0x7FFu;
      const u32 w0 = ((__builtin_bit_cast(u32, hv[0]) + 0x400u) & 0xFFFFF800u) | tagc;
      const u32 w1 = ((__builtin_bit_cast(u32, hv[1]) + 0x400u) & 0xFFFFF800u) | tagc;
      const u64 pk = (u64)w0 | ((u64)w1 << 32);
      const int b = (bg << 4) + crow;
      const size_t eidx = ((size_t)((s & 1) * 2 + dirv)) * 256 * 128 + b * 128 + (sl << 4) + (u0 >> 1);
      __hip_atomic_store(exch + eidx, pk, __ATOMIC_RELAXED, __HIP_MEMORY_SCOPE_AGENT);

      union { u16 hw[2]; u32 pkh; } uh;
      uh.hw[0] = __builtin_bit_cast(u16, (f16)hv[0]);
      uh.hw[1] = __builtin_bit_cast(u16, (f16)hv[1]);
      const int uoff = (dirv << 7) + (sl << 4) + (u0 >> 1);
      if constexpr (L == 0) {
        ((u32*)hA)[((size_t)t_or * 256 + b) * 256 + uoff] = uh.pkh;
      } else if constexpr (L == 1) {
        if (s < 256)
          ((u32*)aux)[((size_t)(dirv * 256 + s) * 256 + b) * 128 + (sl << 4) + (u0 >> 1)] = uh.pkh;
        else
          ((u32*)hA)[((size_t)t_or * 256 + b) * 256 + uoff] = uh.pkh;
      } else {
        if (t_or == S_ - 1)
          ((u32*)l2out)[(size_t)b * 256 + uoff] = uh.pkh;
      }
    }

    // ---- L1: crossover MAGIC after h(254) globally posted ----
    if constexpr (L == 1) {
      if (s == 254) {
        asm volatile("s_waitcnt vmcnt(0)" ::: "memory");
        __syncthreads();
        if (tid == 0)
          __hip_atomic_store(xprog + dirv * 128 + (bg << 3) + sl, MAGIC_,
                             __ATOMIC_RELAXED, __HIP_MEMORY_SCOPE_AGENT);
      }
    }

    // ---- write x_s for s+1 and pre-compute its x-part ----
    if (pf) {
#pragma unroll
      for (int i = 0; i < XI; ++i) {
        const int G = tid + (i << 8);
        if (NG < 256 && G >= NG) break;
        const int row = G >> LG, g = G & (GPR - 1);
        *(f16x8*)&x_s[row * KIN + ((g ^ (row & 7)) << 3)] = xreg[i];
      }
      __syncthreads();
      accx0 = (f32x4){}; accx1 = (f32x4){};
      X_MFMA(accx0, accx1);
    }
  }
#undef X_MFMA
}

// ---------------------------------------------------------------------------
__global__ __launch_bounds__(256) void fc_head(
    const f16* __restrict__ l2out,   // [B][512]
    const float* __restrict__ fc1_w, const float* __restrict__ fc1_b,
    const float* __restrict__ fc2_w, const float* __restrict__ fc2_b,
    const float* __restrict__ fc3_w, const float* __restrict__ fc3_b,
    float* __restrict__ out)
{
  __shared__ float last[512];
  __shared__ float h1[256];
  __shared__ float h2[128];
  const int b = blockIdx.x;
  const int t = threadIdx.x;
  for (int i = t; i < 512; i += 256)
    last[i] = (float)l2out[(size_t)b * 512 + i];
  __syncthreads();
  {
    float a = fc1_b[t];
    for (int k = 0; k < 512; ++k) a = fmaf(last[k], fc1_w[t * 512 + k], a);
    h1[t] = fmaxf(a, 0.f);
  }
  __syncthreads();
  if (t < 128) {
    float a = fc2_b[t];
    for (int k = 0; k < 256; ++k) a = fmaf(h1[k], fc2_w[t * 256 + k], a);
    h2[t] = fmaxf(a, 0.f);
  }
  __syncthreads();
  if (t == 0) {
    float a = fc3_b[0];
    for (int k = 0; k < 128; ++k) a = fmaf(h2[k], fc3_w[k], a);
    out[b] = a;
  }
}

__global__ void sentinel(float* out, int n, float v) {
  const int i = blockIdx.x * blockDim.x + threadIdx.x;
  if (i < n) out[i] = v;
}

// ---------------------------------------------------------------------------
extern "C" void kernel_launch(void* const* d_in, const int* in_sizes, int n_in,
                              void* d_out, int out_size, void* d_ws, size_t ws_size,
                              hipStream_t stream) {
  (void)in_sizes; (void)n_in;
  const float* x      = (const float*)d_in[0];
  const float* w_ih0  = (const float*)d_in[1];
  const float* w_hh0  = (const float*)d_in[2];
  const float* b0     = (const float*)d_in[3];
  const float* w_ih_r = (const float*)d_in[4];
  const float* w_hh_r = (const float*)d_in[5];
  const float* b_r    = (const float*)d_in[6];
  const float* fc1_w  = (const float*)d_in[7];
  const float* fc1_b  = (const float*)d_in[8];
  const float* fc2_w  = (const float*)d_in[9];
  const float* fc2_b  = (const float*)d_in[10];
  const float* fc3_w  = (const float*)d_in[11];
  const float* fc3_b  = (const float*)d_in[12];
  float* out = (float*)d_out;

  // ---- workspace carve (bytes) ----
  const size_t off_hA    = 0;
  const size_t off_aux   = off_hA    + (size_t)512*256*512*2;      // 128 MiB
  const size_t off_xT    = off_aux   + (size_t)2*256*256*256*2;    // +64 MiB
  const size_t off_l2o   = off_xT    + (size_t)512*256*64*2;       // +16 MiB
  const size_t off_exch  = off_l2o   + (size_t)256*512*2;          // +0.25 MiB
  const size_t off_xprog = off_exch  + (size_t)2*2*256*128*8;      // +1 MiB
  const size_t need      = off_xprog + 1024;
  if (ws_size < need) {
    sentinel<<<1, 256, 0, stream>>>(out, out_size, (float)(ws_size >> 20));
    return;
  }
  char* ws = (char*)d_ws;
  f16* hA    = (f16*)(ws + off_hA);
  f16* aux   = (f16*)(ws + off_aux);
  f16* xT    = (f16*)(ws + off_xT);
  f16* l2out = (f16*)(ws + off_l2o);
  u64* exch  = (u64*)(ws + off_exch);
  u32* xprog = (u32*)(ws + off_xprog);

  // kill stale tags / MAGIC from previous replays (0xAA aliases no (L,s) tag)
  hipMemsetAsync(ws + off_exch, 0xAA, (size_t)2*2*256*128*8 + 1024, stream);

  transpose_x<<<512, 256, 0, stream>>>(x, xT);

  lstm_layer<0, 64><<<256, 256, 0, stream>>>(
      xT, hA, aux, l2out, exch, xprog, w_ih0, w_hh0, b0);
  lstm_layer<1, 512><<<256, 256, 0, stream>>>(
      xT, hA, aux, l2out, exch, xprog, w_ih_r, w_hh_r, b_r);
  lstm_layer<2, 512><<<256, 256, 0, stream>>>(
      xT, hA, aux, l2out, exch, xprog,
      w_ih_r + (size_t)2 * 1024 * 512, w_hh_r + (size_t)2 * 1024 * 256,
      b_r + 2048);

  fc_head<<<B_, 256, 0, stream>>>(l2out, fc1_w, fc1_b, fc2_w, fc2_b, fc3_w, fc3_b, out);
}